// Round 8
// baseline (1287.409 us; speedup 1.0000x reference)
//
#include <hip/hip_runtime.h>
#include <stdint.h>

// Problem constants
#define B_   4
#define P_   20000
#define NB_  9
#define WN_  17
#define CI_  64
#define CO_  128
#define PTS  32            // points per block -> 4 waves, each = 1 batch row x 32 points x CO=128
#define NBLK (P_ / PTS)    // 625 blocks

typedef __fp16 f16x8 __attribute__((ext_vector_type(8)));
typedef __fp16 h2    __attribute__((ext_vector_type(2)));
typedef float  f32x16 __attribute__((ext_vector_type(16)));

union H2U { h2 h; uint32_t u; };
union F8U { f16x8 v; h2 h[4]; uint4 u; };

// wsb granule (16B = 8 f16) index: (((m*2+pass)*4 + oloc)*128 + co)*8 ushorts.
// Consecutive co are contiguous -> a wave's 32-lane fragment load is 512B dense.
__global__ void prep_wm(const float* __restrict__ w, ushort* __restrict__ wsb) {
    int i = blockIdx.x * 256 + threadIdx.x;     // 0 .. 17407 (17*2*4*128)
    int m2p  = i >> 9;                          // m*2+pass
    int r    = i & 511;
    int oloc = r >> 7, co = r & 127;
    int m = m2p >> 1, p = m2p & 1;
    const float* src = w + (size_t)m * (CO_ * CI_) + co * CI_ + (p * 4 + oloc) * 8;
    float4 v0 = *(const float4*)(src);
    float4 v1 = *(const float4*)(src + 4);
    F8U h;
    h.h[0] = __builtin_amdgcn_cvt_pkrtz(v0.x, v0.y);
    h.h[1] = __builtin_amdgcn_cvt_pkrtz(v0.z, v0.w);
    h.h[2] = __builtin_amdgcn_cvt_pkrtz(v1.x, v1.y);
    h.h[3] = __builtin_amdgcn_cvt_pkrtz(v1.z, v1.w);
    *(uint4*)&wsb[(size_t)((m2p * 4 + oloc) * 128 + co) * 8] = h.u;
}

// Round-8: revert to the round-1 structure (best measured: ~93us dispatch).
// Session evidence: barriers at 2 waves/SIMD cost more than the L2 panel
// re-reads they save (rounds 4/6); (256,3) always spills or crashes (rounds
// 2/5/7). Single change vs round 1: full-iteration B-prefetch -- unroll m by
// 2 with ping-pong fragment buffers so all 8 B-loads for iter m+1 are issued
// at the TOP of iter m (>=1 full iteration of slack vs round 1's ~half-iter),
// with no per-iter register copies. ~168 arch + 64 AGPR < 256: no spill.
// Canary: WRITE_SIZE ~40 MB, VGPR <= ~165.
template <bool PRE>
__global__ __launch_bounds__(256, 2)
void lasm_fused(const float* __restrict__ in_pc,    // (B,P,CI)    f32
                const float* __restrict__ raw_w,    // (P,NB,WN)   f32
                const float* __restrict__ weights,  // (WN,CO*CI)  f32
                const float* __restrict__ bias,     // (P,CO)      f32
                const int*   __restrict__ nbr,      // (P,NB)      int32
                const ushort* __restrict__ wsb,     // pre-swizzled f16 panel
                float*       __restrict__ out)      // (B,P,CO)    f32
{
    // stride 33 pads: staging writes (addr step 297 words -> bank step 9) and
    // reads (32 consecutive words per (m,n)) are both conflict-free.
    __shared__ __align__(16) uint32_t s_w2[WN_ * NB_ * 33];   // ~20.2 KB

    const int tid  = threadIdx.x;
    const int lane = tid & 63;
    const int wv   = tid >> 6;        // batch row 0..3 (one wave per batch)
    const int arow = lane & 31;       // point-local index / A-row / co within co-tile
    const int q    = lane >> 5;       // k-half
    const int p0   = blockIdx.x * PTS;

    const size_t binpc = (size_t)wv * P_ * CI_;

    h2 x[NB_][8];
    auto gather = [&](int pass) {
        const int ch0 = pass * 32 + q * 8;
        #pragma unroll
        for (int n = 0; n < NB_; ++n) {
            uint32_t nid = (uint32_t)nbr[(size_t)(p0 + arow) * NB_ + n];
            if (nid < (uint32_t)P_) {
                const float* src = in_pc + binpc + (size_t)nid * CI_ + ch0;
                float4 a0 = *(const float4*)(src);
                float4 a1 = *(const float4*)(src + 4);
                float4 b0 = *(const float4*)(src + 16);
                float4 b1 = *(const float4*)(src + 20);
                x[n][0] = __builtin_amdgcn_cvt_pkrtz(a0.x, a0.y);
                x[n][1] = __builtin_amdgcn_cvt_pkrtz(a0.z, a0.w);
                x[n][2] = __builtin_amdgcn_cvt_pkrtz(a1.x, a1.y);
                x[n][3] = __builtin_amdgcn_cvt_pkrtz(a1.z, a1.w);
                x[n][4] = __builtin_amdgcn_cvt_pkrtz(b0.x, b0.y);
                x[n][5] = __builtin_amdgcn_cvt_pkrtz(b0.z, b0.w);
                x[n][6] = __builtin_amdgcn_cvt_pkrtz(b1.x, b1.y);
                x[n][7] = __builtin_amdgcn_cvt_pkrtz(b1.z, b1.w);
            } else {
                h2 z = {(__fp16)0.f, (__fp16)0.f};
                #pragma unroll
                for (int j = 0; j < 8; ++j) x[n][j] = z;
            }
        }
    };

    // ---- prologue staging (the ONLY barrier in the kernel) ----
    gather(0);
    for (int idx = tid; idx < PTS * NB_ * WN_; idx += 256) {
        int pl2 = idx / (NB_ * WN_);
        int rem = idx % (NB_ * WN_);
        int n   = rem / WN_;
        int m   = rem % WN_;
        float wf = raw_w[(size_t)p0 * NB_ * WN_ + idx];
        H2U c; c.h = __builtin_amdgcn_cvt_pkrtz(wf, wf);
        s_w2[(m * NB_ + n) * 33 + pl2] = c.u;
    }
    __syncthreads();

    f32x16 acc[4];
    #pragma unroll
    for (int c = 0; c < 4; ++c)
        #pragma unroll
        for (int j = 0; j < 16; ++j) acc[c][j] = 0.f;

    // B-fragment load, direct global->VGPR (L2-resident panel, no LDS, no barrier)
    // t = kk*4 + c
    auto load_b = [&](int m, int pass, int t) -> f16x8 {
        const int kk = t >> 2, c = t & 3;
        const int oloc = kk * 2 + q;
        if (PRE) {
            F8U r;
            r.u = *(const uint4*)&wsb[(size_t)(((m * 2 + pass) * 4 + oloc) * 128
                                               + c * 32 + arow) * 8];
            return r.v;
        } else {
            const float* s = weights + (size_t)m * (CO_ * CI_)
                           + (c * 32 + arow) * CI_ + (pass * 4 + oloc) * 8;
            float4 v0 = *(const float4*)(s);
            float4 v1 = *(const float4*)(s + 4);
            F8U r;
            r.h[0] = __builtin_amdgcn_cvt_pkrtz(v0.x, v0.y);
            r.h[1] = __builtin_amdgcn_cvt_pkrtz(v0.z, v0.w);
            r.h[2] = __builtin_amdgcn_cvt_pkrtz(v1.x, v1.y);
            r.h[3] = __builtin_amdgcn_cvt_pkrtz(v1.z, v1.w);
            return r.v;
        }
    };

    // stage-1 + 8 MFMAs for one m, consuming a prefetched 8-fragment buffer
    auto do_m = [&](int m, const f16x8 (&bf)[8]) {
        H2U wc[NB_];
        #pragma unroll
        for (int n = 0; n < NB_; ++n) wc[n].u = s_w2[(m * NB_ + n) * 33 + arow];

        F8U f[2];
        #pragma unroll
        for (int kk = 0; kk < 2; ++kk) {
            #pragma unroll
            for (int r4 = 0; r4 < 4; ++r4) {
                h2 c2 = {(__fp16)0.f, (__fp16)0.f};
                #pragma unroll
                for (int n = 0; n < NB_; ++n) c2 += wc[n].h * x[n][kk * 4 + r4];
                f[kk].h[r4] = c2;
            }
        }
        #pragma unroll
        for (int c = 0; c < 4; ++c)
            acc[c] = __builtin_amdgcn_mfma_f32_32x32x16_f16(f[0].v, bf[c],     acc[c], 0, 0, 0);
        #pragma unroll
        for (int c = 0; c < 4; ++c)
            acc[c] = __builtin_amdgcn_mfma_f32_32x32x16_f16(f[1].v, bf[4 + c], acc[c], 0, 0, 0);
    };

    // ---- barrier-free m-loop, unrolled by 2 with ping-pong prefetch ----
    // All 8 fragments for iter m+1 are in flight across the whole of iter m.
    auto mloop = [&](int pass) {
        f16x8 bufA[8], bufB[8];
        #pragma unroll
        for (int t = 0; t < 8; ++t) bufA[t] = load_b(0, pass, t);

        for (int m = 0; m < WN_ - 1; m += 2) {       // m = 0,2,...,14
            #pragma unroll
            for (int t = 0; t < 8; ++t) bufB[t] = load_b(m + 1, pass, t);
            do_m(m, bufA);
            const int m2 = (m + 2 < WN_) ? m + 2 : WN_ - 1;
            #pragma unroll
            for (int t = 0; t < 8; ++t) bufA[t] = load_b(m2, pass, t);
            do_m(m + 1, bufB);
        }
        do_m(WN_ - 1, bufA);                         // m=16 tail (loaded at m=14)
    };

    mloop(0);
    gather(1);     // pass-1 gathers issue while pass-0 MFMAs drain
    mloop(1);

    // ---- epilogue: bias + ELU + nontemporal fp32 store ----
    #pragma unroll
    for (int c = 0; c < 4; ++c) {
        int col = c * 32 + arow;
        #pragma unroll
        for (int v = 0; v < 16; ++v) {
            int lr = (v & 3) + 8 * (v >> 2) + 4 * q;   // local row 0..31 in M-tile
            int p  = p0 + lr;
            float val = acc[c][v] + bias[(size_t)p * CO_ + col];
            val = (val > 0.f) ? val : (__expf(val) - 1.f);
            __builtin_nontemporal_store(val, &out[((size_t)wv * P_ + p) * CO_ + col]);
        }
    }
}

extern "C" void kernel_launch(void* const* d_in, const int* in_sizes, int n_in,
                              void* d_out, int out_size, void* d_ws, size_t ws_size,
                              hipStream_t stream) {
    const float* in_pc   = (const float*)d_in[0];
    const float* raw_w   = (const float*)d_in[1];
    const float* weights = (const float*)d_in[2];
    const float* bias    = (const float*)d_in[3];
    const int*   nbr     = (const int*)  d_in[4];
    float* out = (float*)d_out;

    const size_t need = (size_t)WN_ * 2 * 4096 * sizeof(ushort);   // 278,528 B
    if (d_ws != nullptr && ws_size >= need) {
        ushort* wsb = (ushort*)d_ws;
        prep_wm<<<dim3(WN_ * 2 * 512 / 256), dim3(256), 0, stream>>>(weights, wsb);
        lasm_fused<true><<<dim3(NBLK), dim3(256), 0, stream>>>(
            in_pc, raw_w, weights, bias, nbr, wsb, out);
    } else {
        lasm_fused<false><<<dim3(NBLK), dim3(256), 0, stream>>>(
            in_pc, raw_w, weights, bias, nbr, nullptr, out);
    }
}

// Round 9
// 358.969 us; speedup vs baseline: 3.5864x; 3.5864x over previous
//
#include <hip/hip_runtime.h>
#include <stdint.h>

// Problem constants
#define B_   4
#define P_   20000
#define NB_  9
#define WN_  17
#define CI_  64
#define CO_  128
#define PTS  16            // points per block -> 4 waves: (mt = batch-pair) x (ch = co-half)
#define NBLK (P_ / PTS)    // 1250 blocks

typedef __fp16 f16x8 __attribute__((ext_vector_type(8)));
typedef __fp16 h2    __attribute__((ext_vector_type(2)));
typedef float  f32x16 __attribute__((ext_vector_type(16)));

union H2U { h2 h; uint32_t u; };
union F8U { f16x8 v; h2 h[4]; uint4 u; };

// wsb granule (16B = 8 f16 = 8 consecutive ci), section-major (round-4 layout):
//   G = ((s*WN_ + m)*2 + q)*128 + co,  s = pass*2+kk,  source ci = s*16 + q*8 .. +7
__global__ void prep_wm(const float* __restrict__ w, ushort* __restrict__ wsb) {
    int i = blockIdx.x * 256 + threadIdx.x;     // 0 .. 17407
    int co = i & 127;
    int t  = i >> 7;
    int q  = t & 1;  t >>= 1;
    int m  = t % WN_;
    int s  = t / WN_;                            // pass*2 + kk
    const float* src = w + (size_t)m * (CO_ * CI_) + co * CI_ + s * 16 + q * 8;
    float4 v0 = *(const float4*)(src);
    float4 v1 = *(const float4*)(src + 4);
    F8U h;
    h.h[0] = __builtin_amdgcn_cvt_pkrtz(v0.x, v0.y);
    h.h[1] = __builtin_amdgcn_cvt_pkrtz(v0.z, v0.w);
    h.h[2] = __builtin_amdgcn_cvt_pkrtz(v1.x, v1.y);
    h.h[3] = __builtin_amdgcn_cvt_pkrtz(v1.z, v1.w);
    *(uint4*)&wsb[(size_t)i * 8] = h.u;
}

// Round-9: break the AGPR wall. Session evidence: (256,3) with acc[4]=64 AGPR
// always spills (R2/R5/R7); barriers at low occupancy lose (R4/R6); manual
// deep pipelines via array-ref lambdas alloca-spill (R8: FETCH+WRITE ~2GB at
// VGPR=108). This round: co-split across waves (round-0 layout, acc[2]=32
// AGPR, proven 84 arch VGPR @ (256,3) with NO spill) + kk-split (round-4,
// x=36) + barrier-free fully-unrolled m-sections so the COMPILER schedules
// B-prefetch into its reg slack. Stage-1/gather duplicate x2 (known round-0
// cost) in exchange for 3+ waves/SIMD TLP.
// Canaries: WRITE ~40 MB, VGPR <= ~135, Occupancy >= 22%.
template <bool PRE>
__global__ __launch_bounds__(256, 3)
void lasm_fused(const float* __restrict__ in_pc,    // (B,P,CI)    f32
                const float* __restrict__ raw_w,    // (P,NB,WN)   f32
                const float* __restrict__ weights,  // (WN,CO*CI)  f32
                const float* __restrict__ bias,     // (P,CO)      f32
                const int*   __restrict__ nbr,      // (P,NB)      int32
                const ushort* __restrict__ wsb,     // pre-swizzled f16 panel
                float*       __restrict__ out)      // (B,P,CO)    f32
{
    // stride 17, pl in [0,16): 16 consecutive words per (m,n); lanes l and
    // l+16 read the same word (broadcast) -> conflict-free. 10.4 KB.
    __shared__ __align__(16) uint32_t s_w2[WN_ * NB_ * 17];

    const int tid  = threadIdx.x;
    const int lane = tid & 63;
    const int wv   = tid >> 6;
    const int arow = lane & 31;       // A-row / co within co-tile
    const int q    = lane >> 5;       // k-half within the section's K=16
    const int mt   = wv >> 1;         // batch pair: rows are batches 2mt, 2mt+1
    const int ch   = wv & 1;          // co half: cols ch*64 .. ch*64+63
    const int p0   = blockIdx.x * PTS;
    const int pl   = arow & 15;       // point-local index
    const int brow = mt * 2 + (arow >> 4);          // this lane's batch
    const size_t binpc = (size_t)brow * P_ * CI_;

    // neighbor ids hoisted once (9 regs)
    uint32_t nid[NB_];
    #pragma unroll
    for (int n = 0; n < NB_; ++n)
        nid[n] = (uint32_t)nbr[(size_t)(p0 + pl) * NB_ + n];

    h2 x[NB_][4];                      // 36 regs: this section's 8 ci per lane
    auto gather = [&](int s) {
        const int ch0 = s * 16 + q * 8;
        #pragma unroll
        for (int n = 0; n < NB_; ++n) {
            if (nid[n] < (uint32_t)P_) {
                const float* src = in_pc + binpc + (size_t)nid[n] * CI_ + ch0;
                float4 a0 = *(const float4*)(src);
                float4 a1 = *(const float4*)(src + 4);
                x[n][0] = __builtin_amdgcn_cvt_pkrtz(a0.x, a0.y);
                x[n][1] = __builtin_amdgcn_cvt_pkrtz(a0.z, a0.w);
                x[n][2] = __builtin_amdgcn_cvt_pkrtz(a1.x, a1.y);
                x[n][3] = __builtin_amdgcn_cvt_pkrtz(a1.z, a1.w);
            } else {
                h2 z = {(__fp16)0.f, (__fp16)0.f};
                #pragma unroll
                for (int j = 0; j < 4; ++j) x[n][j] = z;
            }
        }
    };

    // ---- prologue staging (the ONLY barrier in the kernel) ----
    gather(0);
    for (int idx = tid; idx < PTS * NB_ * WN_; idx += 256) {
        int pl2 = idx / (NB_ * WN_);
        int rem = idx % (NB_ * WN_);
        int n   = rem / WN_;
        int m   = rem % WN_;
        float wf = raw_w[(size_t)p0 * NB_ * WN_ + idx];
        H2U c; c.h = __builtin_amdgcn_cvt_pkrtz(wf, wf);
        s_w2[(m * NB_ + n) * 17 + pl2] = c.u;
    }
    __syncthreads();

    f32x16 acc0, acc1;                 // 32 AGPR total (the point of this round)
    #pragma unroll
    for (int j = 0; j < 16; ++j) { acc0[j] = 0.f; acc1[j] = 0.f; }

    // ---- 4 barrier-free sections, each fully unrolled over 17 m ----
    for (int s = 0; s < 4; ++s) {
        if (s) gather(s);              // s=0 gathered in prologue
        #pragma unroll
        for (int m = 0; m < WN_; ++m) {
            // per-lane w for its point
            H2U wc[NB_];
            #pragma unroll
            for (int n = 0; n < NB_; ++n) wc[n].u = s_w2[(m * NB_ + n) * 17 + pl];

            // stage-1: A-fragment for this (s, m)
            F8U fa;
            #pragma unroll
            for (int r4 = 0; r4 < 4; ++r4) {
                h2 c2 = {(__fp16)0.f, (__fp16)0.f};
                #pragma unroll
                for (int n = 0; n < NB_; ++n) c2 += wc[n].h * x[n][r4];
                fa.h[r4] = c2;
            }

            // B fragments: this wave's co-half, 2 co-tiles of 32
            F8U b0, b1;
            if (PRE) {
                const size_t gb = ((size_t)((s * WN_ + m) * 2 + q) * 128
                                   + ch * 64 + arow) * 8;
                b0.u = *(const uint4*)&wsb[gb];
                b1.u = *(const uint4*)&wsb[gb + 32 * 8];
            } else {
                const float* sp = weights + (size_t)m * (CO_ * CI_)
                                + (ch * 64 + arow) * CI_ + s * 16 + q * 8;
                float4 v0 = *(const float4*)(sp);
                float4 v1 = *(const float4*)(sp + 4);
                b0.h[0] = __builtin_amdgcn_cvt_pkrtz(v0.x, v0.y);
                b0.h[1] = __builtin_amdgcn_cvt_pkrtz(v0.z, v0.w);
                b0.h[2] = __builtin_amdgcn_cvt_pkrtz(v1.x, v1.y);
                b0.h[3] = __builtin_amdgcn_cvt_pkrtz(v1.z, v1.w);
                const float* sp1 = sp + 32 * CI_;
                float4 w0 = *(const float4*)(sp1);
                float4 w1 = *(const float4*)(sp1 + 4);
                b1.h[0] = __builtin_amdgcn_cvt_pkrtz(w0.x, w0.y);
                b1.h[1] = __builtin_amdgcn_cvt_pkrtz(w0.z, w0.w);
                b1.h[2] = __builtin_amdgcn_cvt_pkrtz(w1.x, w1.y);
                b1.h[3] = __builtin_amdgcn_cvt_pkrtz(w1.z, w1.w);
            }

            acc0 = __builtin_amdgcn_mfma_f32_32x32x16_f16(fa.v, b0.v, acc0, 0, 0, 0);
            acc1 = __builtin_amdgcn_mfma_f32_32x32x16_f16(fa.v, b1.v, acc1, 0, 0, 0);
        }
    }

    // ---- epilogue: bias + ELU + nontemporal fp32 store (round-0 mapping) ----
    #pragma unroll
    for (int c = 0; c < 2; ++c) {
        const int col = ch * 64 + c * 32 + arow;
        #pragma unroll
        for (int v = 0; v < 16; ++v) {
            int lr = (v & 3) + 8 * (v >> 2) + 4 * q;   // local row 0..31
            int b  = mt * 2 + (lr >> 4);
            int p  = p0 + (lr & 15);
            float val = (c == 0 ? acc0[v] : acc1[v]) + bias[(size_t)p * CO_ + col];
            val = (val > 0.f) ? val : (__expf(val) - 1.f);
            __builtin_nontemporal_store(val, &out[((size_t)b * P_ + p) * CO_ + col]);
        }
    }
}

extern "C" void kernel_launch(void* const* d_in, const int* in_sizes, int n_in,
                              void* d_out, int out_size, void* d_ws, size_t ws_size,
                              hipStream_t stream) {
    const float* in_pc   = (const float*)d_in[0];
    const float* raw_w   = (const float*)d_in[1];
    const float* weights = (const float*)d_in[2];
    const float* bias    = (const float*)d_in[3];
    const int*   nbr     = (const int*)  d_in[4];
    float* out = (float*)d_out;

    const size_t need = (size_t)4 * WN_ * 2 * 128 * 8 * sizeof(ushort);   // 278,528 B
    if (d_ws != nullptr && ws_size >= need) {
        ushort* wsb = (ushort*)d_ws;
        prep_wm<<<dim3(68), dim3(256), 0, stream>>>(weights, wsb);
        lasm_fused<true><<<dim3(NBLK), dim3(256), 0, stream>>>(
            in_pc, raw_w, weights, bias, nbr, wsb, out);
    } else {
        lasm_fused<false><<<dim3(NBLK), dim3(256), 0, stream>>>(
            in_pc, raw_w, weights, bias, nbr, nullptr, out);
    }
}